// Round 12
// baseline (266.186 us; speedup 1.0000x reference)
//
#include <hip/hip_runtime.h>

// Mandelbrot counts — R6-proven bit-exact arithmetic + compaction + wave-
// aggregated enqueue (R8) + packed fp32 fused z-block (R14) + 4px/lane
// kernels (R14/R16) + FIRST-BOUNDARY-AT-8 compaction ladder (R20).
//
// R19 post-mortem: (1) __launch_bounds__(256,4)+8px made stage A WORSE
// (VGPR 28->40, occ 76->51%, 77.5->96us) — min-waves hint degraded the
// allocator; reverted to R14's proven 4px/plain-bounds A. (2) 3-node vs
// 5-node totals differ <3us -> dispatch boundaries are CHEAP; the ~235us
// plateau is work distribution. Phase work: A(16 on all px)=268M px-checks
// (57% of pipeline), ~134M wasted on early escapers + 58M on closed-form
// shortcut px. R20 moves the first compaction boundary 16->8:
//   A: checks 0..7 (134M) -> q0 (S(8)~2.5-3.1M records)
//   S1: 8..15 (8)   q0->q1   (~26M checks)   [new, cheap]
//   S2: 16..55 (40) q1->q0   (77M)
//   S3: 56..135 (80) q0->q1  (64M)
//   S4: 136..255 (120) finish (64M)
// Total ~365M vs 473M checks (-23%). Needs q capacity ~3.2M records ->
// gated at seg_cap2>=60000; else R16-proven 16-split; overflow-inline is
// correct in all cases.
//
// Proven bit-exact sequence per check (absmax=0 lineage R6..R19):
//   zi2=fl(zi*zi); mag=fma(zr,zr,zi2); t=fma(zr,zr,-zi2)  [VOP3P neg mod]
//   zr'=fl(t+cr); t2=fl(zr+zr); zi'=fma(t2,zi,ci)
//   act=(mag<4)?act:0 (sticky, NaN-safe); cnt+=act (exact small-int add)
// Cardioid/bulb shortcut margin 1e-3 (HW-validated).
//
// d_ws: [0,4096) 64 lines x 64B; line dwords +0,+4,+8,+12 = ctr0..ctr3.
// q0 recs @4096 (float4 seg-major, idx after), q1 after q0. Overflow at any
// enqueue -> finish inline (correct, slower). Tiny ws -> mono fallback.

#define MAX_ITERS 256

typedef __attribute__((ext_vector_type(2))) float f32x2;
typedef __attribute__((ext_vector_type(4))) float f32x4;

// ---------- scalar proven body (fallback + overflow inline) ----------
__device__ __forceinline__ float mul32(float a, float b) {
    float d; asm("v_mul_f32 %0, %1, %2" : "=v"(d) : "v"(a), "v"(b)); return d;
}
__device__ __forceinline__ float add32(float a, float b) {
    float d; asm("v_add_f32 %0, %1, %2" : "=v"(d) : "v"(a), "v"(b)); return d;
}
__device__ __forceinline__ float fma32(float a, float b, float c) {
    float d; asm("v_fma_f32 %0, %1, %2, %3" : "=v"(d) : "v"(a), "v"(b), "v"(c)); return d;
}
__device__ __forceinline__ float fma32_negc(float a, float b, float c) {
    float d; asm("v_fma_f32 %0, %1, %2, -%3" : "=v"(d) : "v"(a), "v"(b), "v"(c)); return d;
}

__device__ __forceinline__ void iter_checks(float cr, float ci,
                                            float& zr, float& zi,
                                            float& act, float& cnt, int nchecks)
{
    #pragma unroll 8
    for (int s = 0; s < nchecks; ++s) {
        const float zi2 = mul32(zi, zi);
        const float mag = fma32(zr, zr, zi2);
        act = (mag < 4.0f) ? act : 0.0f;
        cnt = cnt + act;
        const float t   = fma32_negc(zr, zr, zi2);
        const float nr  = add32(t, cr);
        const float t2  = add32(zr, zr);
        zi = fma32(t2, zi, ci);
        zr = nr;
    }
}

// ---------- fused packed z-step: exactly 6 v_pk ops, mag out ----------
__device__ __forceinline__ void zstep2(const f32x2 cr, const f32x2 ci,
                                       f32x2& zr, f32x2& zi, f32x2& mag)
{
    f32x2 s, t, u;
    asm("v_pk_mul_f32 %0, %5, %5\n\t"                                   // s   = zi*zi
        "v_pk_fma_f32 %1, %4, %4, %0\n\t"                               // mag = zr*zr + s
        "v_pk_fma_f32 %2, %4, %4, %0 neg_lo:[0,0,1] neg_hi:[0,0,1]\n\t" // t = zr*zr - s
        "v_pk_add_f32 %3, %4, %4\n\t"                                   // u   = zr + zr
        "v_pk_add_f32 %4, %2, %6\n\t"                                   // zr' = t + cr
        "v_pk_fma_f32 %5, %3, %5, %7"                                   // zi' = u*zi + ci
        : "=&v"(s), "=&v"(mag), "=&v"(t), "=&v"(u), "+v"(zr), "+v"(zi)
        : "v"(cr), "v"(ci));
}

// One check over 4 pixels (two streams). Bookkeeping is the PROVEN C form.
__device__ __forceinline__ void check4(
    const f32x2 crA, const f32x2 ciA, f32x2& zrA, f32x2& ziA,
    const f32x2 crB, const f32x2 ciB, f32x2& zrB, f32x2& ziB,
    float& act0, float& act1, float& act2, float& act3,
    float& cnt0, float& cnt1, float& cnt2, float& cnt3)
{
    f32x2 magA, magB;
    zstep2(crA, ciA, zrA, ziA, magA);
    zstep2(crB, ciB, zrB, ziB, magB);
    act0 = (magA.x < 4.0f) ? act0 : 0.0f;  cnt0 += act0;
    act1 = (magA.y < 4.0f) ? act1 : 0.0f;  cnt1 += act1;
    act2 = (magB.x < 4.0f) ? act2 : 0.0f;  cnt2 += act2;
    act3 = (magB.y < 4.0f) ? act3 : 0.0f;  cnt3 += act3;
}

__device__ __forceinline__ int lane_id() {
    return __builtin_amdgcn_mbcnt_hi(~0u, __builtin_amdgcn_mbcnt_lo(~0u, 0));
}

__device__ __forceinline__ bool in_shortcut(float cr, float ci) {
    const float xq = cr - 0.25f;
    const float q  = xq * xq + ci * ci;
    const bool in_card = (q * (q + xq) - 0.25f * ci * ci) < -1e-3f;
    const float xb = cr + 1.0f;
    const bool in_bulb = (xb * xb + ci * ci) < (0.0625f - 1e-3f);
    return in_card | in_bulb;
}

// ---------- stage A: 4 px/thread, ACHECKS checks, enqueue to q0 ----------
// Plain __launch_bounds__(256): R14-proven lean codegen (VGPR 28).
template <int ACHECKS>
__global__ __launch_bounds__(256) void mandel_stage_a_q(
    const float* __restrict__ c_real, const float* __restrict__ c_imag,
    float* __restrict__ out, unsigned char* __restrict__ ws,
    unsigned seg_cap, int n)
{
    const int tq = blockIdx.x * blockDim.x + threadIdx.x;
    const int p0 = tq << 2;
    if (p0 >= n) return;

    if (p0 + 3 >= n) {  // ragged tail (n%4!=0): finish fully inline, scalar
        for (int j = 0; j < 4 && p0 + j < n; ++j) {
            const float cr = c_real[p0 + j], ci = c_imag[p0 + j];
            if (in_shortcut(cr, ci)) { out[p0 + j] = 256.0f; continue; }
            float zr = cr, zi = ci, act = 1.0f, cnt = 0.0f;
            iter_checks(cr, ci, zr, zi, act, cnt, MAX_ITERS);
            out[p0 + j] = cnt;
        }
        return;
    }

    const f32x4 cr4 = *(const f32x4*)(c_real + p0);
    const f32x4 ci4 = *(const f32x4*)(c_imag + p0);
    const f32x2 crA = {cr4.x, cr4.y}, ciA = {ci4.x, ci4.y};
    const f32x2 crB = {cr4.z, cr4.w}, ciB = {ci4.z, ci4.w};
    const bool sc0 = in_shortcut(cr4.x, ci4.x);
    const bool sc1 = in_shortcut(cr4.y, ci4.y);
    const bool sc2 = in_shortcut(cr4.z, ci4.z);
    const bool sc3 = in_shortcut(cr4.w, ci4.w);

    f32x2 zrA = crA, ziA = ciA, zrB = crB, ziB = ciB;
    float act0 = 1.0f, act1 = 1.0f, act2 = 1.0f, act3 = 1.0f;
    float cnt0 = 0.0f, cnt1 = 0.0f, cnt2 = 0.0f, cnt3 = 0.0f;
    #pragma unroll
    for (int s = 0; s < ACHECKS; ++s)   // checks z_0..z_{ACHECKS-1}
        check4(crA, ciA, zrA, ziA, crB, ciB, zrB, ziB,
               act0, act1, act2, act3, cnt0, cnt1, cnt2, cnt3);

    const bool sv0 = (!sc0) && (act0 != 0.0f);
    const bool sv1 = (!sc1) && (act1 != 0.0f);
    const bool sv2 = (!sc2) && (act2 != 0.0f);
    const bool sv3 = (!sc3) && (act3 != 0.0f);

    const unsigned long long m0 = __ballot(sv0);
    const unsigned long long m1 = __ballot(sv1);
    const unsigned long long m2 = __ballot(sv2);
    const unsigned long long m3 = __ballot(sv3);
    const unsigned long long any = m0 | m1 | m2 | m3;
    if (any != 0ull) {
        const int lane = lane_id();
        const int leader = (int)__ffsll(any) - 1;
        const int seg = blockIdx.x & 63;
        unsigned* ctr = (unsigned*)(ws + (size_t)seg * 64u);
        const unsigned c0 = (unsigned)__popcll(m0);
        const unsigned c1 = (unsigned)__popcll(m1);
        const unsigned c2 = (unsigned)__popcll(m2);
        unsigned base = 0u;
        if (lane == leader)
            base = atomicAdd(ctr, c0 + c1 + c2 + (unsigned)__popcll(m3));
        base = (unsigned)__shfl((int)base, leader, 64);
        float4* qf = (float4*)(ws + 4096);
        int*    qi = (int*)(ws + 4096 + (size_t)seg_cap * 64u * 16u);
        const unsigned long long below = (1ull << lane) - 1ull;
        const size_t segbase = (size_t)seg * seg_cap;

        float zrv[4] = {zrA.x, zrA.y, zrB.x, zrB.y};
        float ziv[4] = {ziA.x, ziA.y, ziB.x, ziB.y};
        float crv[4] = {cr4.x, cr4.y, cr4.z, cr4.w};
        float civ[4] = {ci4.x, ci4.y, ci4.z, ci4.w};
        float cnv[4] = {cnt0, cnt1, cnt2, cnt3};
        const bool svv[4] = {sv0, sv1, sv2, sv3};
        const unsigned prev[4] = {0u, c0, c0 + c1, c0 + c1 + c2};
        const unsigned long long mv[4] = {m0, m1, m2, m3};
        #pragma unroll
        for (int j = 0; j < 4; ++j) {
            if (!svv[j]) continue;
            const unsigned slot = base + prev[j] +
                (unsigned)__popcll(mv[j] & below);
            if (slot < seg_cap) {
                qf[segbase + slot] = make_float4(zrv[j], ziv[j], crv[j], civ[j]);
                qi[segbase + slot] = p0 + j;
            } else {   // overflow: finish inline with proven scalar body
                float zrs = zrv[j], zis = ziv[j], as = 1.0f, cs = cnv[j];
                iter_checks(crv[j], civ[j], zrs, zis, as, cs,
                            MAX_ITERS - ACHECKS);
                out[p0 + j] = cs;
            }
        }
    }
    if (!sv0) out[p0 + 0] = sc0 ? 256.0f : cnt0;
    if (!sv1) out[p0 + 1] = sc1 ? 256.0f : cnt1;
    if (!sv2) out[p0 + 2] = sc2 ? 256.0f : cnt2;
    if (!sv3) out[p0 + 3] = sc3 ? 256.0f : cnt3;
}

// ---------- strip: NCHECKS on 4 records/thread, optional requeue ----------
// Plain __launch_bounds__(256): 8/40/80/120 instantiations compile lean
// (R16-proven); the R18 blowup was at 70/170.
template <int NCHECKS, int START, bool HAS_DST>
__global__ __launch_bounds__(256) void mandel_strip_q(
    float* __restrict__ out, unsigned char* __restrict__ ws,
    const float4* __restrict__ srcF, const int* __restrict__ srcI,
    float4* __restrict__ dstF, int* __restrict__ dstI,
    int src_ctr, int dst_ctr, unsigned seg_cap, int blocks_per_seg)
{
    const int seg = (int)(blockIdx.x & 63u);
    const int grp = (int)(blockIdx.x >> 6);
    const unsigned cnt_s = __hip_atomic_load(
        (const unsigned*)(ws + (size_t)seg * 64u + (size_t)src_ctr * 4u),
        __ATOMIC_RELAXED, __HIP_MEMORY_SCOPE_AGENT);
    const unsigned nq = (cnt_s < seg_cap) ? cnt_s : seg_cap;
    const unsigned q = (nq + 3u) >> 2;
    const unsigned stride = (unsigned)blocks_per_seg * 256u;
    const size_t segbase = (size_t)seg * seg_cap;
    const int lane = lane_id();

    for (unsigned k = (unsigned)grp * 256u + threadIdx.x; k < q; k += stride) {
        const unsigned i1 = k + q, i2 = k + 2u * q, i3 = k + 3u * q;
        const bool v1 = (i1 < nq), v2 = (i2 < nq), v3 = (i3 < nq);
        const float4 r0 = srcF[segbase + k];
        const float4 r1 = v1 ? srcF[segbase + i1] : r0;
        const float4 r2 = v2 ? srcF[segbase + i2] : r0;
        const float4 r3 = v3 ? srcF[segbase + i3] : r0;
        const int idx0 = srcI[segbase + k];
        const int idx1 = v1 ? srcI[segbase + i1] : -1;
        const int idx2 = v2 ? srcI[segbase + i2] : -1;
        const int idx3 = v3 ? srcI[segbase + i3] : -1;

        f32x2 zrA = {r0.x, r1.x}, ziA = {r0.y, r1.y};
        f32x2 crA = {r0.z, r1.z}, ciA = {r0.w, r1.w};
        f32x2 zrB = {r2.x, r3.x}, ziB = {r2.y, r3.y};
        f32x2 crB = {r2.z, r3.z}, ciB = {r2.w, r3.w};
        float act0 = 1.0f, act1 = v1 ? 1.0f : 0.0f;
        float act2 = v2 ? 1.0f : 0.0f, act3 = v3 ? 1.0f : 0.0f;
        float cnt0 = (float)START, cnt1 = (float)START;
        float cnt2 = (float)START, cnt3 = (float)START;
        #pragma unroll 8
        for (int s = 0; s < NCHECKS; ++s)
            check4(crA, ciA, zrA, ziA, crB, ciB, zrB, ziB,
                   act0, act1, act2, act3, cnt0, cnt1, cnt2, cnt3);

        if (HAS_DST) {
            const bool sv0 = (act0 != 0.0f);
            const bool sv1 = (act1 != 0.0f);   // invalid halves stay dead
            const bool sv2 = (act2 != 0.0f);
            const bool sv3 = (act3 != 0.0f);
            const unsigned long long m0 = __ballot(sv0);
            const unsigned long long m1 = __ballot(sv1);
            const unsigned long long m2 = __ballot(sv2);
            const unsigned long long m3 = __ballot(sv3);
            const unsigned long long any = m0 | m1 | m2 | m3;
            if (any != 0ull) {
                const int leader = (int)__ffsll(any) - 1;
                unsigned* ctr = (unsigned*)(ws + (size_t)seg * 64u
                                               + (size_t)dst_ctr * 4u);
                const unsigned c0 = (unsigned)__popcll(m0);
                const unsigned c1 = (unsigned)__popcll(m1);
                const unsigned c2 = (unsigned)__popcll(m2);
                unsigned base = 0u;
                if (lane == leader)
                    base = atomicAdd(ctr, c0 + c1 + c2 + (unsigned)__popcll(m3));
                base = (unsigned)__shfl((int)base, leader, 64);
                const unsigned long long below = (1ull << lane) - 1ull;

                const float zrv[4] = {zrA.x, zrA.y, zrB.x, zrB.y};
                const float ziv[4] = {ziA.x, ziA.y, ziB.x, ziB.y};
                const float crv[4] = {crA.x, crA.y, crB.x, crB.y};
                const float civ[4] = {ciA.x, ciA.y, ciB.x, ciB.y};
                const float cnv[4] = {cnt0, cnt1, cnt2, cnt3};
                const int  idxv[4] = {idx0, idx1, idx2, idx3};
                const bool svv[4] = {sv0, sv1, sv2, sv3};
                const unsigned prev[4] = {0u, c0, c0 + c1, c0 + c1 + c2};
                const unsigned long long mvv[4] = {m0, m1, m2, m3};
                #pragma unroll
                for (int j = 0; j < 4; ++j) {
                    if (!svv[j]) continue;
                    const unsigned slot = base + prev[j] +
                        (unsigned)__popcll(mvv[j] & below);
                    if (slot < seg_cap) {
                        dstF[segbase + slot] =
                            make_float4(zrv[j], ziv[j], crv[j], civ[j]);
                        dstI[segbase + slot] = idxv[j];
                    } else {   // overflow: finish inline (correct, slower)
                        float zrs = zrv[j], zis = ziv[j], as = 1.0f, cs = cnv[j];
                        iter_checks(crv[j], civ[j], zrs, zis, as, cs,
                                    256 - START - NCHECKS);
                        out[idxv[j]] = cs;
                    }
                }
            }
            if (!sv0) out[idx0] = cnt0;          // escaped this strip
            if (v1 && !sv1) out[idx1] = cnt1;
            if (v2 && !sv2) out[idx2] = cnt2;
            if (v3 && !sv3) out[idx3] = cnt3;
        } else {
            out[idx0] = cnt0;                    // final strip
            if (v1) out[idx1] = cnt1;
            if (v2) out[idx2] = cnt2;
            if (v3) out[idx3] = cnt3;
        }
    }
}

// ---------- proven scalar fallback (tiny ws only) ----------
__global__ __launch_bounds__(256) void mandel_mono(
    const float* __restrict__ c_real, const float* __restrict__ c_imag,
    float* __restrict__ out, int n)
{
    int i = blockIdx.x * blockDim.x + threadIdx.x;
    if (i >= n) return;
    const float cr = c_real[i], ci = c_imag[i];
    float zr = cr, zi = ci, act = 1.0f, cnt = 0.0f;
    iter_checks(cr, ci, zr, zi, act, cnt, MAX_ITERS);
    out[i] = cnt;
}

extern "C" void kernel_launch(void* const* d_in, const int* in_sizes, int n_in,
                              void* d_out, int out_size, void* d_ws, size_t ws_size,
                              hipStream_t stream)
{
    const float* c_real = (const float*)d_in[0];
    const float* c_imag = (const float*)d_in[1];
    float* out = (float*)d_out;
    const int n = in_sizes[0];  // 4096*4096
    const int block = 256;

    unsigned char* ws = (unsigned char*)d_ws;
    const size_t avail = (ws_size > 4096) ? (ws_size - 4096) : 0;
    const unsigned seg_cap1 = (unsigned)(avail / (64u * 20u));        // 1 queue
    const unsigned seg_cap2 = (unsigned)(avail / (64u * 20u * 2u));   // 2 queues

    if (seg_cap1 < 8192u) {  // ws too small for compaction: proven fallback
        const int gridA = (n + block - 1) / block;
        mandel_mono<<<gridA, block, 0, stream>>>(c_real, c_imag, out, n);
        return;
    }

    // zero the 64 counter lines (graph-legal async memset, no extra kernel)
    hipMemsetAsync(ws, 0, 4096, stream);

    const int nquads = (n + 3) / 4;
    const int gridA = (nquads + block - 1) / block;

    if (seg_cap2 >= 60000u) {
        // R20: first boundary at 8 (needs ~3.2M record capacity; have 3.84M+).
        const unsigned sc = seg_cap2;
        float4* q0f = (float4*)(ws + 4096);
        int*    q0i = (int*)(ws + 4096 + (size_t)sc * 64u * 16u);
        float4* q1f = (float4*)(ws + 4096 + (size_t)sc * 64u * 20u);
        int*    q1i = (int*)(ws + 4096 + (size_t)sc * 64u * 20u
                                       + (size_t)sc * 64u * 16u);

        mandel_stage_a_q<8><<<gridA, block, 0, stream>>>(c_real, c_imag, out,
                                                         ws, sc, n);
        // S1: checks 8..15 (8), q0 -> q1 (ctr 0 -> ctr 1)
        mandel_strip_q<8, 8, true><<<64 * 32, block, 0, stream>>>(
            out, ws, q0f, q0i, q1f, q1i, 0, 1, sc, 32);
        // S2: checks 16..55 (40), q1 -> q0 (ctr 1 -> ctr 2)
        mandel_strip_q<40, 16, true><<<64 * 32, block, 0, stream>>>(
            out, ws, q1f, q1i, q0f, q0i, 1, 2, sc, 32);
        // S3: checks 56..135 (80), q0 -> q1 (ctr 2 -> ctr 3)
        mandel_strip_q<80, 56, true><<<64 * 16, block, 0, stream>>>(
            out, ws, q0f, q0i, q1f, q1i, 2, 3, sc, 16);
        // S4: checks 136..255 (120), finish (ctr 3)
        mandel_strip_q<120, 136, false><<<64 * 16, block, 0, stream>>>(
            out, ws, q1f, q1i, (float4*)nullptr, (int*)nullptr, 3, 0, sc, 16);
        return;
    }

    if (seg_cap2 >= 33000u) {
        // R16-proven 16-split ladder.
        const unsigned sc = seg_cap2;
        float4* q0f = (float4*)(ws + 4096);
        int*    q0i = (int*)(ws + 4096 + (size_t)sc * 64u * 16u);
        float4* q1f = (float4*)(ws + 4096 + (size_t)sc * 64u * 20u);
        int*    q1i = (int*)(ws + 4096 + (size_t)sc * 64u * 20u
                                       + (size_t)sc * 64u * 16u);

        mandel_stage_a_q<16><<<gridA, block, 0, stream>>>(c_real, c_imag, out,
                                                          ws, sc, n);
        mandel_strip_q<40, 16, true><<<64 * 32, block, 0, stream>>>(
            out, ws, q0f, q0i, q1f, q1i, 0, 1, sc, 32);
        mandel_strip_q<80, 56, true><<<64 * 16, block, 0, stream>>>(
            out, ws, q1f, q1i, q0f, q0i, 1, 2, sc, 16);
        mandel_strip_q<120, 136, false><<<64 * 16, block, 0, stream>>>(
            out, ws, q0f, q0i, (float4*)nullptr, (int*)nullptr, 2, 0, sc, 16);
        return;
    }

    // Single-queue path: stage A(16) + fixed-240 stage B.
    mandel_stage_a_q<16><<<gridA, block, 0, stream>>>(c_real, c_imag, out,
                                                      ws, seg_cap1, n);
    mandel_strip_q<240, 16, false><<<64 * 32, block, 0, stream>>>(
        out, ws,
        (const float4*)(ws + 4096),
        (const int*)(ws + 4096 + (size_t)seg_cap1 * 64u * 16u),
        (float4*)nullptr, (int*)nullptr, 0, 0, seg_cap1, 32);
}

// Round 13
// 237.147 us; speedup vs baseline: 1.1225x; 1.1225x over previous
//
#include <hip/hip_runtime.h>

// Mandelbrot counts — R6-proven bit-exact arithmetic + packed fp32 fused
// z-block (R14) + wave-aggregated enqueue (R8), restructured as a SINGLE
// FUSED KERNEL with block-local LDS compaction (R21).
//
// R20 post-mortem: A(8 checks)=81us vs A(16)=77.5 with VALUBusy 45% vs 75%
// -> stage A is pinned by fixed memory/enqueue work, not arithmetic. B-
// section invariant ~150-160us across 4x compute variation; R14-vs-R12
// ledger consistent only with ~15-25us per dispatch boundary. The pipeline
// is boundary/fixed-cost dominated -> fuse everything.
//
// R21: one kernel, one graph node, no global queues, no memset:
//   * block grid-strides over 1024-px groups; per group: proven 16-check
//     A-phase (4px/lane), non-survivors write out, survivors pushed to an
//     LDS pool (wave ballot + ONE LDS atomicAdd per wave).
//   * pool >= 1024 -> drain: each thread takes exactly 4 records (2 packed
//     streams) and runs the proven fixed-240 body at 100% lane density.
//   * final drain is thread-granular: threads with no records skip (check4
//     needs no cross-lane ops), so partial drains waste almost nothing.
//   * all sync is __syncthreads() (block-local, XCD-safe, graph-safe).
//   * pool 1280 recs = 25.6KB LDS -> 6 blocks/CU = 24 waves/CU (matches
//     stage A's measured-best occupancy). Pool overflow (P~0, variance
//     margin 5 sigma) -> proven inline-finish path.
// Removes: 2 dispatch boundaries (~30-50us), 76MB queue HBM traffic, the
// counter memset. A/B phases overlap naturally across blocks.
//
// Proven bit-exact sequence per check (absmax=0 lineage R6..R20):
//   zi2=fl(zi*zi); mag=fma(zr,zr,zi2); t=fma(zr,zr,-zi2)  [VOP3P neg mod]
//   zr'=fl(t+cr); t2=fl(zr+zr); zi'=fma(t2,zi,ci)
//   act=(mag<4)?act:0 (sticky, NaN-safe); cnt+=act (exact small-int add)
// Drain records restart act=1, cnt=16 == proven stage-B semantics.
// Cardioid/bulb shortcut margin 1e-3 (HW-validated).
// VGPR watch (R18 lesson): plain __launch_bounds__(256); check VGPR_Count.

#define MAX_ITERS 256
#define POOL_CAP 1280
#define DRAIN_AT 1024

typedef __attribute__((ext_vector_type(2))) float f32x2;
typedef __attribute__((ext_vector_type(4))) float f32x4;

// ---------- scalar proven body (ragged tail + pool-overflow inline) ----------
__device__ __forceinline__ float mul32(float a, float b) {
    float d; asm("v_mul_f32 %0, %1, %2" : "=v"(d) : "v"(a), "v"(b)); return d;
}
__device__ __forceinline__ float add32(float a, float b) {
    float d; asm("v_add_f32 %0, %1, %2" : "=v"(d) : "v"(a), "v"(b)); return d;
}
__device__ __forceinline__ float fma32(float a, float b, float c) {
    float d; asm("v_fma_f32 %0, %1, %2, %3" : "=v"(d) : "v"(a), "v"(b), "v"(c)); return d;
}
__device__ __forceinline__ float fma32_negc(float a, float b, float c) {
    float d; asm("v_fma_f32 %0, %1, %2, -%3" : "=v"(d) : "v"(a), "v"(b), "v"(c)); return d;
}

__device__ __forceinline__ void iter_checks(float cr, float ci,
                                            float& zr, float& zi,
                                            float& act, float& cnt, int nchecks)
{
    #pragma unroll 8
    for (int s = 0; s < nchecks; ++s) {
        const float zi2 = mul32(zi, zi);
        const float mag = fma32(zr, zr, zi2);
        act = (mag < 4.0f) ? act : 0.0f;
        cnt = cnt + act;
        const float t   = fma32_negc(zr, zr, zi2);
        const float nr  = add32(t, cr);
        const float t2  = add32(zr, zr);
        zi = fma32(t2, zi, ci);
        zr = nr;
    }
}

// ---------- fused packed z-step: exactly 6 v_pk ops, mag out ----------
__device__ __forceinline__ void zstep2(const f32x2 cr, const f32x2 ci,
                                       f32x2& zr, f32x2& zi, f32x2& mag)
{
    f32x2 s, t, u;
    asm("v_pk_mul_f32 %0, %5, %5\n\t"                                   // s   = zi*zi
        "v_pk_fma_f32 %1, %4, %4, %0\n\t"                               // mag = zr*zr + s
        "v_pk_fma_f32 %2, %4, %4, %0 neg_lo:[0,0,1] neg_hi:[0,0,1]\n\t" // t = zr*zr - s
        "v_pk_add_f32 %3, %4, %4\n\t"                                   // u   = zr + zr
        "v_pk_add_f32 %4, %2, %6\n\t"                                   // zr' = t + cr
        "v_pk_fma_f32 %5, %3, %5, %7"                                   // zi' = u*zi + ci
        : "=&v"(s), "=&v"(mag), "=&v"(t), "=&v"(u), "+v"(zr), "+v"(zi)
        : "v"(cr), "v"(ci));
}

// One check over 4 pixels (two streams). Bookkeeping is the PROVEN C form.
__device__ __forceinline__ void check4(
    const f32x2 crA, const f32x2 ciA, f32x2& zrA, f32x2& ziA,
    const f32x2 crB, const f32x2 ciB, f32x2& zrB, f32x2& ziB,
    float& act0, float& act1, float& act2, float& act3,
    float& cnt0, float& cnt1, float& cnt2, float& cnt3)
{
    f32x2 magA, magB;
    zstep2(crA, ciA, zrA, ziA, magA);
    zstep2(crB, ciB, zrB, ziB, magB);
    act0 = (magA.x < 4.0f) ? act0 : 0.0f;  cnt0 += act0;
    act1 = (magA.y < 4.0f) ? act1 : 0.0f;  cnt1 += act1;
    act2 = (magB.x < 4.0f) ? act2 : 0.0f;  cnt2 += act2;
    act3 = (magB.y < 4.0f) ? act3 : 0.0f;  cnt3 += act3;
}

__device__ __forceinline__ int lane_id() {
    return __builtin_amdgcn_mbcnt_hi(~0u, __builtin_amdgcn_mbcnt_lo(~0u, 0));
}

__device__ __forceinline__ bool in_shortcut(float cr, float ci) {
    const float xq = cr - 0.25f;
    const float q  = xq * xq + ci * ci;
    const bool in_card = (q * (q + xq) - 0.25f * ci * ci) < -1e-3f;
    const float xb = cr + 1.0f;
    const bool in_bulb = (xb * xb + ci * ci) < (0.0625f - 1e-3f);
    return in_card | in_bulb;
}

// Drain body: 240 checks on up to 4 records (2 packed streams), guarded
// writes. Invalid slots run garbage arithmetic (harmless, proven pattern).
__device__ __forceinline__ void drain4(
    const float4 r0, const float4 r1, const float4 r2, const float4 r3,
    const bool v0, const bool v1, const bool v2, const bool v3,
    const int i0, const int i1, const int i2, const int i3,
    float* __restrict__ out)
{
    f32x2 zrA; zrA.x = r0.x; zrA.y = r1.x;
    f32x2 ziA; ziA.x = r0.y; ziA.y = r1.y;
    f32x2 crA; crA.x = r0.z; crA.y = r1.z;
    f32x2 ciA; ciA.x = r0.w; ciA.y = r1.w;
    f32x2 zrB; zrB.x = r2.x; zrB.y = r3.x;
    f32x2 ziB; ziB.x = r2.y; ziB.y = r3.y;
    f32x2 crB; crB.x = r2.z; crB.y = r3.z;
    f32x2 ciB; ciB.x = r2.w; ciB.y = r3.w;
    float act0 = v0 ? 1.0f : 0.0f, act1 = v1 ? 1.0f : 0.0f;
    float act2 = v2 ? 1.0f : 0.0f, act3 = v3 ? 1.0f : 0.0f;
    float cnt0 = 16.0f, cnt1 = 16.0f, cnt2 = 16.0f, cnt3 = 16.0f;
    #pragma unroll 8
    for (int s = 0; s < 240; ++s)       // checks z_16..z_255
        check4(crA, ciA, zrA, ziA, crB, ciB, zrB, ziB,
               act0, act1, act2, act3, cnt0, cnt1, cnt2, cnt3);
    if (v0) out[i0] = cnt0;
    if (v1) out[i1] = cnt1;
    if (v2) out[i2] = cnt2;
    if (v3) out[i3] = cnt3;
}

// ---------- the single fused kernel ----------
__global__ __launch_bounds__(256) void mandel_fused(
    const float* __restrict__ c_real, const float* __restrict__ c_imag,
    float* __restrict__ out, int n)
{
    __shared__ float4 poolF[POOL_CAP];
    __shared__ int    poolI[POOL_CAP];
    __shared__ int    pool_cnt;

    const int tid = (int)threadIdx.x;
    const int lane = lane_id();
    if (tid == 0) pool_cnt = 0;
    __syncthreads();

    const int ngroups = (n + 1023) >> 10;     // 1024-px groups

    for (int g = (int)blockIdx.x; g < ngroups; g += (int)gridDim.x) {
        const int p0 = (g << 10) + (tid << 2);
        if (p0 < n) {
            if (p0 + 3 >= n) {
                // ragged tail: finish fully inline, proven scalar (no enqueue)
                for (int j = 0; j < 4 && p0 + j < n; ++j) {
                    const float cr = c_real[p0 + j], ci = c_imag[p0 + j];
                    if (in_shortcut(cr, ci)) { out[p0 + j] = 256.0f; continue; }
                    float zr = cr, zi = ci, act = 1.0f, cnt = 0.0f;
                    iter_checks(cr, ci, zr, zi, act, cnt, MAX_ITERS);
                    out[p0 + j] = cnt;
                }
            } else {
                // ---- A-phase: proven 16 checks on 4 px ----
                const f32x4 cr4 = *(const f32x4*)(c_real + p0);
                const f32x4 ci4 = *(const f32x4*)(c_imag + p0);
                f32x2 crA; crA.x = cr4.x; crA.y = cr4.y;
                f32x2 ciA; ciA.x = ci4.x; ciA.y = ci4.y;
                f32x2 crB; crB.x = cr4.z; crB.y = cr4.w;
                f32x2 ciB; ciB.x = ci4.z; ciB.y = ci4.w;
                const bool sc0 = in_shortcut(cr4.x, ci4.x);
                const bool sc1 = in_shortcut(cr4.y, ci4.y);
                const bool sc2 = in_shortcut(cr4.z, ci4.z);
                const bool sc3 = in_shortcut(cr4.w, ci4.w);

                f32x2 zrA = crA, ziA = ciA, zrB = crB, ziB = ciB;
                float act0 = 1.0f, act1 = 1.0f, act2 = 1.0f, act3 = 1.0f;
                float cnt0 = 0.0f, cnt1 = 0.0f, cnt2 = 0.0f, cnt3 = 0.0f;
                #pragma unroll
                for (int s = 0; s < 16; ++s)     // checks z_0..z_15
                    check4(crA, ciA, zrA, ziA, crB, ciB, zrB, ziB,
                           act0, act1, act2, act3, cnt0, cnt1, cnt2, cnt3);

                const bool sv0 = (!sc0) && (act0 != 0.0f);
                const bool sv1 = (!sc1) && (act1 != 0.0f);
                const bool sv2 = (!sc2) && (act2 != 0.0f);
                const bool sv3 = (!sc3) && (act3 != 0.0f);

                // ---- wave-aggregated enqueue to the LDS pool ----
                const unsigned long long m0 = __ballot(sv0);
                const unsigned long long m1 = __ballot(sv1);
                const unsigned long long m2 = __ballot(sv2);
                const unsigned long long m3 = __ballot(sv3);
                const unsigned long long any = m0 | m1 | m2 | m3;
                if (any != 0ull) {
                    const int leader = (int)__ffsll(any) - 1;
                    const unsigned c0 = (unsigned)__popcll(m0);
                    const unsigned c1 = (unsigned)__popcll(m1);
                    const unsigned c2 = (unsigned)__popcll(m2);
                    int base_i = 0;
                    if (lane == leader)
                        base_i = atomicAdd(&pool_cnt,
                            (int)(c0 + c1 + c2 + (unsigned)__popcll(m3)));
                    const unsigned base =
                        (unsigned)__shfl(base_i, leader, 64);
                    const unsigned long long below = (1ull << lane) - 1ull;

                    const float zrv[4] = {zrA.x, zrA.y, zrB.x, zrB.y};
                    const float ziv[4] = {ziA.x, ziA.y, ziB.x, ziB.y};
                    const float crv[4] = {cr4.x, cr4.y, cr4.z, cr4.w};
                    const float civ[4] = {ci4.x, ci4.y, ci4.z, ci4.w};
                    const float cnv[4] = {cnt0, cnt1, cnt2, cnt3};
                    const bool svv[4] = {sv0, sv1, sv2, sv3};
                    const unsigned prev[4] = {0u, c0, c0 + c1, c0 + c1 + c2};
                    const unsigned long long mv[4] = {m0, m1, m2, m3};
                    #pragma unroll
                    for (int j = 0; j < 4; ++j) {
                        if (!svv[j]) continue;
                        const unsigned slot = base + prev[j] +
                            (unsigned)__popcll(mv[j] & below);
                        if (slot < POOL_CAP) {
                            poolF[slot] = make_float4(zrv[j], ziv[j],
                                                      crv[j], civ[j]);
                            poolI[slot] = p0 + j;
                        } else {
                            // pool overflow (P~0): proven inline finish
                            float zrs = zrv[j], zis = ziv[j];
                            float as = 1.0f, cs = cnv[j];
                            iter_checks(crv[j], civ[j], zrs, zis, as, cs, 240);
                            out[p0 + j] = cs;
                        }
                    }
                }
                // non-survivors write out now (escaped early or shortcut)
                if (!sv0) out[p0 + 0] = sc0 ? 256.0f : cnt0;
                if (!sv1) out[p0 + 1] = sc1 ? 256.0f : cnt1;
                if (!sv2) out[p0 + 2] = sc2 ? 256.0f : cnt2;
                if (!sv3) out[p0 + 3] = sc3 ? 256.0f : cnt3;
            }
        }
        __syncthreads();
        // ---- drain when full (uniform branch: pool_cnt read post-sync) ----
        const int cnt = pool_cnt;
        if (cnt >= DRAIN_AT) {
            const float4 r0 = poolF[tid];
            const float4 r1 = poolF[tid + 256];
            const float4 r2 = poolF[tid + 512];
            const float4 r3 = poolF[tid + 768];
            const int i0 = poolI[tid];
            const int i1 = poolI[tid + 256];
            const int i2 = poolI[tid + 512];
            const int i3 = poolI[tid + 768];
            __syncthreads();   // all drain reads complete
            // move residual records down; update count
            const int eff = (cnt < POOL_CAP) ? cnt : POOL_CAP;
            for (int t = tid; t < eff - DRAIN_AT; t += 256) {
                poolF[t] = poolF[DRAIN_AT + t];
                poolI[t] = poolI[DRAIN_AT + t];
            }
            if (tid == 0) pool_cnt = eff - DRAIN_AT;
            // proven fixed-240 body at full density
            drain4(r0, r1, r2, r3, true, true, true, true,
                   i0, i1, i2, i3, out);
        }
        __syncthreads();       // move + count visible before next enqueue
    }

    // ---- final drain (thread-granular: record-less threads skip) ----
    int cnt = pool_cnt;
    if (cnt > POOL_CAP) cnt = POOL_CAP;
    const int i0 = tid, i1 = tid + 256, i2 = tid + 512, i3 = tid + 768;
    const bool v0 = i0 < cnt, v1 = i1 < cnt, v2 = i2 < cnt, v3 = i3 < cnt;
    if (v0 | v1 | v2 | v3) {
        const float4 r0 = v0 ? poolF[i0] : make_float4(0.f, 0.f, 0.f, 0.f);
        const float4 r1 = v1 ? poolF[i1] : r0;
        const float4 r2 = v2 ? poolF[i2] : r0;
        const float4 r3 = v3 ? poolF[i3] : r0;
        drain4(r0, r1, r2, r3, v0, v1, v2, v3,
               v0 ? poolI[i0] : 0, v1 ? poolI[i1] : 0,
               v2 ? poolI[i2] : 0, v3 ? poolI[i3] : 0, out);
    }
}

extern "C" void kernel_launch(void* const* d_in, const int* in_sizes, int n_in,
                              void* d_out, int out_size, void* d_ws, size_t ws_size,
                              hipStream_t stream)
{
    const float* c_real = (const float*)d_in[0];
    const float* c_imag = (const float*)d_in[1];
    float* out = (float*)d_out;
    const int n = in_sizes[0];  // 4096*4096

    // 1536 blocks = 6/CU (LDS-capped by the 25.6KB pool) = 24 waves/CU,
    // matching stage A's measured-best occupancy. Grid-stride covers all
    // groups; ~10-11 groups/block -> ~1 full mid-drain + one ~80%-full
    // final drain (thread-granular, so partial fill wastes almost nothing).
    const int ngroups = (n + 1023) >> 10;
    int grid = 1536;
    if (grid > ngroups) grid = (ngroups > 0) ? ngroups : 1;
    mandel_fused<<<grid, 256, 0, stream>>>(c_real, c_imag, out, n);
}